// Round 12
// baseline (1533.153 us; speedup 1.0000x reference)
//
#include <hip/hip_runtime.h>
#include <cstddef>

#define B_   8
#define N_   8192
#define M_   2048
#define K_   32
#define DIN_ 13
#define NWRK 240           // sa worker blocks
#define NBLK (8 + NWRK)    // total blocks (<= 256 CUs, 1 block/CU via LDS)

typedef _Float16 f16x8 __attribute__((ext_vector_type(8)));
typedef float    f32x4 __attribute__((ext_vector_type(4)));

// DPP-assisted reduce steps. Invalid source lanes yield identity. VALU-only.
template <int CTRL>
__device__ __forceinline__ float dppmax(float v) {
  int o = __builtin_amdgcn_update_dpp(
      (int)0xff800000, __float_as_int(v), CTRL, 0xF, 0xF, false);  // -inf
  return fmaxf(v, __int_as_float(o));
}
template <int CTRL>
__device__ __forceinline__ unsigned dppminu(unsigned v) {
  unsigned o = (unsigned)__builtin_amdgcn_update_dpp(
      (int)0xFFFFFFFF, (int)v, CTRL, 0xF, 0xF, false);  // u32 max = identity
  return v < o ? v : o;
}
__device__ __forceinline__ float wave_reduce_max(float v) {
  v = dppmax<0x111>(v); v = dppmax<0x112>(v); v = dppmax<0x114>(v);
  v = dppmax<0x118>(v); v = dppmax<0x142>(v); v = dppmax<0x143>(v);
  return __int_as_float(__builtin_amdgcn_readlane(__float_as_int(v), 63));
}
__device__ __forceinline__ unsigned wave_reduce_min_u32(unsigned v) {
  v = dppminu<0x111>(v); v = dppminu<0x112>(v); v = dppminu<0x114>(v);
  v = dppminu<0x118>(v); v = dppminu<0x142>(v); v = dppminu<0x143>(v);
  return (unsigned)__builtin_amdgcn_readlane((int)v, 63);
}

// Intra-wave LDS sync: one wave = one instruction stream; drain LDS ops and
// pin compiler ordering. Replaces __syncthreads() for wave-local sa slices.
#define WAVE_LDS_SYNC()                                   \
  do {                                                    \
    asm volatile("s_waitcnt lgkmcnt(0)" ::: "memory");    \
    __builtin_amdgcn_wave_barrier();                      \
  } while (0)

// ---------------------------------------------------------------------------
// Shared-memory union: fps (135224 B) / 16 per-wave sa slices (100352 B).
// ---------------------------------------------------------------------------
struct FpsLds {
  float px[N_], py[N_], pz[N_];     // 96 KB, ORIGINAL index order
  int   r2o[N_];                    // 32 KB, rank -> orig
  int   vbase[512];
  int   vcur[512];
  int   wsum[8];
  unsigned long long kslot[3];
};
struct __align__(16) SaSlice {
  int      nbr[K_];                 // 128 B
  _Float16 featb[K_][24];           // 1536 B ([32][16] + pad)
  _Float16 h1b[K_][72];             // 4608 B ([32][64] + pad)
};                                  // 6272 B total (16-aligned stride)
union SmemU {
  FpsLds  fps;
  SaSlice sa[16];
};

// ---------------------------------------------------------------------------
// sa math for ONE (b,m), executed by ONE wave on its own LDS slice.
// Byte-identical arithmetic to the verified sa_kernel v2 (r1-r11).
// ---------------------------------------------------------------------------
__device__ __forceinline__ void sa_wave(
    int b, int m, int lane,
    const float* __restrict__ x, const float* __restrict__ pos,
    const float* __restrict__ b1, const float* __restrict__ b2,
    const float* __restrict__ pos_s,
    const _Float16* __restrict__ w1t, const _Float16* __restrict__ w2t,
    float* __restrict__ x_out, SaSlice* sl)
{
  const int l15  = lane & 15;
  const int quad = lane >> 4;

  const float* pb = pos + (size_t)b * N_ * 3;
  const float* xb = x   + (size_t)b * N_ * DIN_;
  const size_t so = ((size_t)b * M_ + m) * 3;
  const float sx = pos_s[so + 0];
  const float sy = pos_s[so + 1];
  const float sz = pos_s[so + 2];
  const float R2 = (float)(0.2 * 0.2);

  // --- ball query: first K in-ball neighbors in index order (EXACT fp32) ---
  int cnt = 0;
  for (int base = 0; base < N_ && cnt < K_; base += 64) {
    int j = base + lane;
    float qx = pb[j * 3 + 0], qy = pb[j * 3 + 1], qz = pb[j * 3 + 2];
    bool win;
    {
#pragma clang fp contract(off)
      float dx = sx - qx, dy = sy - qy, dz = sz - qz;
      float d2 = (dx * dx + dy * dy) + dz * dz;
      win = d2 <= R2;
    }
    unsigned long long mk = __ballot(win);
    int rank = (int)__popcll(mk & ((1ull << lane) - 1ull));
    if (win) {
      int slot = cnt + rank;
      if (slot < K_) sl->nbr[slot] = j;
    }
    cnt += (int)__popcll(mk);
  }
  const int valid = cnt < K_ ? cnt : K_;   // uniform across wave, >= 1
  WAVE_LDS_SYNC();

  // --- gather -> featb (fp16): concat(x_j, pos_j - pos_s), invalid rows 0 ---
  for (int tq = lane; tq < K_ * 16; tq += 64) {
    int r = tq >> 4, i = tq & 15;
    float v = 0.f;
    if (r < valid) {
      int j = sl->nbr[r];
      if (i < DIN_) {
        v = xb[j * DIN_ + i];
      } else {
        float c = (i == 13) ? sx : (i == 14) ? sy : sz;
        float q = pb[j * 3 + (i - 13)];
        v = q - c;
      }
    }
    sl->featb[r][i] = (_Float16)v;
  }
  WAVE_LDS_SYNC();

  f16x8 fz;
#pragma unroll
  for (int i = 0; i < 8; ++i) fz[i] = (_Float16)0;

  // --- A1 / B1 fragments (K=32, k>=16 zero-padded on BOTH operands) ---
  f16x8 a1[2], b1f[4];
#pragma unroll
  for (int mt = 0; mt < 2; ++mt)
    a1[mt] = (quad < 2) ? *(const f16x8*)&sl->featb[mt * 16 + l15][quad * 8]
                        : fz;
#pragma unroll
  for (int nt = 0; nt < 4; ++nt)
    b1f[nt] = (quad < 2) ? *(const f16x8*)&w1t[(nt * 16 + l15) * 16 + quad * 8]
                         : fz;

  // --- MLP1 MFMA + bias + relu -> h1b (fp16) ---
#pragma unroll
  for (int mt = 0; mt < 2; ++mt) {
#pragma unroll
    for (int nt = 0; nt < 4; ++nt) {
      f32x4 c = {0.f, 0.f, 0.f, 0.f};
      c = __builtin_amdgcn_mfma_f32_16x16x32_f16(a1[mt], b1f[nt], c, 0, 0, 0);
      float bb = b1[nt * 16 + l15];
#pragma unroll
      for (int r = 0; r < 4; ++r) {
        float v = c[r] + bb;
        sl->h1b[mt * 16 + quad * 4 + r][nt * 16 + l15] =
            (_Float16)(v > 0.f ? v : 0.f);
      }
    }
  }
  WAVE_LDS_SYNC();

  // --- A2 fragments from h1b ---
  f16x8 a2[2][2];
#pragma unroll
  for (int mt = 0; mt < 2; ++mt)
#pragma unroll
    for (int kt = 0; kt < 2; ++kt)
      a2[mt][kt] = *(const f16x8*)&sl->h1b[mt * 16 + l15][kt * 32 + quad * 8];

  // --- MLP2 per N-tile: 4 MFMA + bias/relu/mask/max + cross-quad reduce ---
  float* o = x_out + ((size_t)b * M_ + m) * 128;
#pragma unroll
  for (int nt = 0; nt < 8; ++nt) {
    f16x8 b20 = *(const f16x8*)&w2t[(nt * 16 + l15) * 64 + 0 * 32 + quad * 8];
    f16x8 b21 = *(const f16x8*)&w2t[(nt * 16 + l15) * 64 + 1 * 32 + quad * 8];
    f32x4 c0 = {0.f, 0.f, 0.f, 0.f}, c1 = {0.f, 0.f, 0.f, 0.f};
    c0 = __builtin_amdgcn_mfma_f32_16x16x32_f16(a2[0][0], b20, c0, 0, 0, 0);
    c0 = __builtin_amdgcn_mfma_f32_16x16x32_f16(a2[0][1], b21, c0, 0, 0, 0);
    c1 = __builtin_amdgcn_mfma_f32_16x16x32_f16(a2[1][0], b20, c1, 0, 0, 0);
    c1 = __builtin_amdgcn_mfma_f32_16x16x32_f16(a2[1][1], b21, c1, 0, 0, 0);
    float bv = b2[nt * 16 + l15];
    float acc = -INFINITY;
#pragma unroll
    for (int r = 0; r < 4; ++r) {
      int row0 = quad * 4 + r;          // rows 0..15  (c0)
      int row1 = 16 + quad * 4 + r;     // rows 16..31 (c1)
      float v0 = c0[r] + bv; v0 = v0 > 0.f ? v0 : 0.f;
      float v1 = c1[r] + bv; v1 = v1 > 0.f ? v1 : 0.f;
      if (row0 < valid) acc = fmaxf(acc, v0);
      if (row1 < valid) acc = fmaxf(acc, v1);
    }
    acc = fmaxf(acc, __shfl_xor(acc, 16));
    acc = fmaxf(acc, __shfl_xor(acc, 32));
    if (quad == 0) o[nt * 16 + l15] = acc;
  }
}

// ---------------------------------------------------------------------------
// Fused cooperative kernel: blocks 0-7 = champion FPS (r4/r9/r11, 1379-1391us,
// bit-exact); blocks 8+ = sa workers, 16 waves/block, each wave one (b,m)
// task, spin-waiting on a per-batch progress counter released by fps every
// 32 selections. Overlaps sa (~105us) under fps (~1380us).
// Correctness: device-scope release (fps t0) / fence-acquire (worker) order
// pos_s visibility across XCDs; cooperative launch guarantees co-residency
// (no spin deadlock); sa slices are wave-private; sa/fps math untouched.
// ---------------------------------------------------------------------------
__global__ __launch_bounds__(1024, 4) void fused_kernel(
    const float* __restrict__ x, const float* __restrict__ pos,
    const float* __restrict__ b1, const float* __restrict__ b2,
    const _Float16* __restrict__ w1t, const _Float16* __restrict__ w2t,
    float* __restrict__ pos_s, float* __restrict__ batch_s,
    float* __restrict__ x_out, int* __restrict__ progress)
{
  __shared__ SmemU u;
  const int t    = threadIdx.x;
  const int lane = t & 63;
  const int wid  = t >> 6;

  if (blockIdx.x < 8) {
    // ======================= FPS path (champion v3) =======================
    const int b = blockIdx.x;
    const float* p = pos + (size_t)b * N_ * 3;

    for (int mm = t; mm < M_; mm += 1024)
      batch_s[b * M_ + mm] = (float)b;
    if (t < 512) u.fps.vcur[t] = 0;
    if (t == 0) { u.fps.kslot[0] = 0ull; u.fps.kslot[1] = 0ull;
                  u.fps.kslot[2] = 0ull; }
    __syncthreads();

    // --- load points + 512-bin Morton histogram ---
    int vid[8];
#pragma unroll
    for (int i = 0; i < 8; ++i) {
      int j = t + 1024 * i;
      float xx = p[j * 3 + 0], yy = p[j * 3 + 1], zz = p[j * 3 + 2];
      u.fps.px[j] = xx; u.fps.py[j] = yy; u.fps.pz[j] = zz;
      int ix = (int)(xx * 8.f); ix = ix < 0 ? 0 : (ix > 7 ? 7 : ix);
      int iy = (int)(yy * 8.f); iy = iy < 0 ? 0 : (iy > 7 ? 7 : iy);
      int iz = (int)(zz * 8.f); iz = iz < 0 ? 0 : (iz > 7 ? 7 : iz);
      int v = (ix & 1) | ((iy & 1) << 1) | ((iz & 1) << 2) |
              (((ix >> 1) & 1) << 3) | (((iy >> 1) & 1) << 4) |
              (((iz >> 1) & 1) << 5) |
              ((ix >> 2) << 6) | ((iy >> 2) << 7) | ((iz >> 2) << 8);
      vid[i] = v;
      atomicAdd(&u.fps.vcur[v], 1);
    }
    __syncthreads();

    // --- exclusive prefix over 512 bins ---
    int h = 0, sc = 0;
    if (t < 512) {
      h = u.fps.vcur[t]; sc = h;
#pragma unroll
      for (int d = 1; d < 64; d <<= 1) {
        int o = __shfl_up(sc, d);
        if (lane >= d) sc += o;
      }
      if (lane == 63) u.fps.wsum[wid] = sc;
    }
    __syncthreads();
    if (t < 8) {
      int v = u.fps.wsum[t]; int inc = v;
#pragma unroll
      for (int d = 1; d < 8; d <<= 1) {
        int o = __shfl_up(inc, d);
        if (t >= d) inc += o;
      }
      u.fps.wsum[t] = inc - v;   // exclusive wave offset
    }
    __syncthreads();
    if (t < 512) { u.fps.vbase[t] = sc - h + u.fps.wsum[t >> 6];
                   u.fps.vcur[t] = 0; }
    __syncthreads();

    // --- scatter: rank per point ---
#pragma unroll
    for (int i = 0; i < 8; ++i) {
      int j = t + 1024 * i;
      int r = u.fps.vbase[vid[i]] + atomicAdd(&u.fps.vcur[vid[i]], 1);
      u.fps.r2o[r] = j;
    }
    __syncthreads();

    // --- gather: thread t owns ranks [8t,8t+8) (spatially tight) ---
    float px[8], py[8], pz[8], mind[8]; int oi[8];
#pragma unroll
    for (int i = 0; i < 8; ++i) {
      int o = u.fps.r2o[t * 8 + i];
      oi[i] = o;
      px[i] = u.fps.px[o]; py[i] = u.fps.py[o]; pz[i] = u.fps.pz[o];
      mind[i] = 1e10f;
    }
#pragma unroll
    for (int i = 0; i < 8; ++i) {
      asm volatile("" : "+v"(px[i]), "+v"(py[i]), "+v"(pz[i]));
    }

    // --- per-LANE bbox of the 8 owned points ---
    float bxmin = px[0], bxmax = px[0], bymin = py[0], bymax = py[0],
          bzmin = pz[0], bzmax = pz[0];
#pragma unroll
    for (int i = 1; i < 8; ++i) {
      bxmin = fminf(bxmin, px[i]); bxmax = fmaxf(bxmax, px[i]);
      bymin = fminf(bymin, py[i]); bymax = fmaxf(bymax, py[i]);
      bzmin = fminf(bzmin, pz[i]); bzmax = fmaxf(bzmax, pz[i]);
    }

    float lx = u.fps.px[0], ly = u.fps.py[0], lz = u.fps.pz[0];
    if (t == 0) {
      pos_s[(size_t)b * M_ * 3 + 0] = lx;
      pos_s[(size_t)b * M_ * 3 + 1] = ly;
      pos_s[(size_t)b * M_ * 3 + 2] = lz;
    }

    float ltm = 1e10f;                  // max of MY 8 minds (exact)
    float cwm = 0.f;                    // cached wave max (uniform)
    unsigned cmin = 0xFFFFFFFFu;        // cached wave tie-min orig idx
    int slm = 1;   // s % 3
    int rsm = 0;   // (s+2) % 3

    for (int s = 1; s < M_; ++s) {
      float cx = fmaxf(fmaxf(bxmin - lx, lx - bxmax), 0.f);
      float cy = fmaxf(fmaxf(bymin - ly, ly - bymax), 0.f);
      float cz = fmaxf(fmaxf(bzmin - lz, lz - bzmax), 0.f);
      float LB = (cx * cx + cy * cy) + cz * cz;
      bool lp = (LB * 0.999999f < ltm);          // lane might change
      if (__ballot(lp) != 0ull) {                // wave-uniform branch
        float tmax;
        {
#pragma clang fp contract(off)
#pragma unroll
          for (int i = 0; i < 8; ++i) {
            float dx = px[i] - lx, dy = py[i] - ly, dz = pz[i] - lz;
            float d  = (dx * dx + dy * dy) + dz * dz;  // EXACT: jnp order
            mind[i]  = fminf(mind[i], d);
          }
          float m0 = fmaxf(mind[0], mind[1]), m1 = fmaxf(mind[2], mind[3]);
          float m2 = fmaxf(mind[4], mind[5]), m3 = fmaxf(mind[6], mind[7]);
          tmax = fmaxf(fmaxf(m0, m1), fmaxf(m2, m3));
        }
        ltm = tmax;
        const float wm = wave_reduce_max(tmax);
        unsigned cc = 0xFFFFFFFFu;   // smallest orig index among my ties
#pragma unroll
        for (int i = 0; i < 8; ++i) {
          unsigned cand = (mind[i] == wm) ? (unsigned)oi[i] : 0xFFFFFFFFu;
          cc = cc < cand ? cc : cand;
        }
        cmin = wave_reduce_min_u32(cc);
        cwm = wm;
      }
      // one submit per wave (fresh or cached)
      if (lane == 0) {
        unsigned long long key =
            ((unsigned long long)__float_as_uint(cwm) << 32) |
            (unsigned long long)(0xFFFFFFFFu - cmin);
        atomicMax(&u.fps.kslot[slm], key);
      }
      __syncthreads();                               // the ONE barrier
      if (t == 0) u.fps.kslot[rsm] = 0ull;
      const unsigned long long kk = u.fps.kslot[slm];
      const int wj  = (int)(0xFFFFFFFFu - (unsigned int)(kk & 0xFFFFFFFFull));
      const int wju = (int)__builtin_amdgcn_readfirstlane(wj);
      lx = u.fps.px[wju]; ly = u.fps.py[wju]; lz = u.fps.pz[wju];
      if (t == 0) {
        size_t o2 = ((size_t)b * M_ + s) * 3;
        pos_s[o2 + 0] = lx; pos_s[o2 + 1] = ly; pos_s[o2 + 2] = lz;
        // release progress every 32 selections (amortized fence cost);
        // s=2047 hits (s&31)==31 -> final release of M_.
        if ((s & 31) == 31)
          __hip_atomic_store(&progress[b], s + 1, __ATOMIC_RELEASE,
                             __HIP_MEMORY_SCOPE_AGENT);
      }
      slm = (slm == 2) ? 0 : slm + 1;
      rsm = (rsm == 2) ? 0 : rsm + 1;
    }
  } else {
    // ======================= SA worker path =======================
    SaSlice* sl = &u.sa[wid];
    const int wgw = (blockIdx.x - 8) * 16 + wid;     // worker wave id
    for (int task = wgw; task < B_ * M_; task += NWRK * 16) {
      const int b = task >> 11, m = task & (M_ - 1);
      if (lane == 0) {
        while (__hip_atomic_load(&progress[b], __ATOMIC_RELAXED,
                                 __HIP_MEMORY_SCOPE_AGENT) <= m)
          __builtin_amdgcn_s_sleep(10);
      }
      __threadfence();   // acquire: fps's pos_s writes now visible
      sa_wave(b, m, lane, x, pos, b1, b2, pos_s, w1t, w2t, x_out, sl);
    }
  }
}

// ---------------------------------------------------------------------------
// Prep: weight transpose/convert + zero the progress counters.
// ---------------------------------------------------------------------------
__global__ __launch_bounds__(256) void prep_kernel(
    const float* __restrict__ W1, const float* __restrict__ W2,
    _Float16* __restrict__ w1t, _Float16* __restrict__ w2t,
    int* __restrict__ progress)
{
  int t = blockIdx.x * 256 + threadIdx.x;
  if (t < 8192) {
    int n = t >> 6, k = t & 63;
    w2t[t] = (_Float16)W2[k * 128 + n];
  }
  int u = t - 8192;
  if (u >= 0 && u < 1024) {
    int n = u >> 4, k = u & 15;
    w1t[u] = (_Float16)W1[k * 64 + n];
  }
  if (blockIdx.x == 0 && threadIdx.x < 8) progress[threadIdx.x] = 0;
}

// ---------------------------------------------------------------------------
extern "C" void kernel_launch(void* const* d_in, const int* in_sizes, int n_in,
                              void* d_out, int out_size, void* d_ws, size_t ws_size,
                              hipStream_t stream) {
  (void)in_sizes; (void)n_in; (void)ws_size; (void)out_size;
  const float* x   = (const float*)d_in[0];
  const float* pos = (const float*)d_in[1];
  // d_in[2] = batch (unused: always broadcast arange(B))
  const float* W1  = (const float*)d_in[3];
  const float* b1  = (const float*)d_in[4];
  const float* W2  = (const float*)d_in[5];
  const float* b2  = (const float*)d_in[6];

  float* out     = (float*)d_out;
  float* x_out   = out;                                  // [B, M, 128]
  float* pos_s   = out + (size_t)B_ * M_ * 128;          // [B, M, 3]
  float* batch_s = pos_s + (size_t)B_ * M_ * 3;          // [B, M]

  _Float16* w1t = (_Float16*)d_ws;                       // [64][16]
  _Float16* w2t = w1t + 1024;                            // [128][64]
  int* progress = (int*)(w2t + 8192);                    // [8]

  prep_kernel<<<36, 256, 0, stream>>>(W1, W2, w1t, w2t, progress);

  void* kargs[] = {
      (void*)&x, (void*)&pos, (void*)&b1, (void*)&b2,
      (void*)&w1t, (void*)&w2t, (void*)&pos_s, (void*)&batch_s,
      (void*)&x_out, (void*)&progress};
  hipLaunchCooperativeKernel((const void*)fused_kernel,
                             dim3(NBLK), dim3(1024), kargs, 0, stream);
}

// Round 13
// 1498.174 us; speedup vs baseline: 1.0233x; 1.0233x over previous
//
#include <hip/hip_runtime.h>
#include <cstddef>

#define B_   8
#define N_   8192
#define M_   2048
#define K_   32
#define DIN_ 13
#define NWRK 240           // sa worker blocks
#define NBLK (8 + NWRK)    // total blocks (<= 256 CUs, 1 block/CU via LDS)

typedef _Float16 f16x8 __attribute__((ext_vector_type(8)));
typedef float    f32x4 __attribute__((ext_vector_type(4)));

// DPP-assisted reduce steps. Invalid source lanes yield identity. VALU-only.
template <int CTRL>
__device__ __forceinline__ float dppmax(float v) {
  int o = __builtin_amdgcn_update_dpp(
      (int)0xff800000, __float_as_int(v), CTRL, 0xF, 0xF, false);  // -inf
  return fmaxf(v, __int_as_float(o));
}
template <int CTRL>
__device__ __forceinline__ unsigned dppminu(unsigned v) {
  unsigned o = (unsigned)__builtin_amdgcn_update_dpp(
      (int)0xFFFFFFFF, (int)v, CTRL, 0xF, 0xF, false);  // u32 max = identity
  return v < o ? v : o;
}
__device__ __forceinline__ float wave_reduce_max(float v) {
  v = dppmax<0x111>(v); v = dppmax<0x112>(v); v = dppmax<0x114>(v);
  v = dppmax<0x118>(v); v = dppmax<0x142>(v); v = dppmax<0x143>(v);
  return __int_as_float(__builtin_amdgcn_readlane(__float_as_int(v), 63));
}
__device__ __forceinline__ unsigned wave_reduce_min_u32(unsigned v) {
  v = dppminu<0x111>(v); v = dppminu<0x112>(v); v = dppminu<0x114>(v);
  v = dppminu<0x118>(v); v = dppminu<0x142>(v); v = dppminu<0x143>(v);
  return (unsigned)__builtin_amdgcn_readlane((int)v, 63);
}

// Intra-wave LDS sync: one wave = one instruction stream; drain LDS ops and
// pin compiler ordering. Replaces __syncthreads() for wave-local sa slices.
#define WAVE_LDS_SYNC()                                   \
  do {                                                    \
    asm volatile("s_waitcnt lgkmcnt(0)" ::: "memory");    \
    __builtin_amdgcn_wave_barrier();                      \
  } while (0)

// ---------------------------------------------------------------------------
// Shared-memory union: fps (135224 B) / 16 per-wave sa slices (100352 B).
// ---------------------------------------------------------------------------
struct FpsLds {
  float px[N_], py[N_], pz[N_];     // 96 KB, ORIGINAL index order
  int   r2o[N_];                    // 32 KB, rank -> orig
  int   vbase[512];
  int   vcur[512];
  int   wsum[8];
  unsigned long long kslot[3];
};
struct __align__(16) SaSlice {
  int      nbr[K_];                 // 128 B
  _Float16 featb[K_][24];           // 1536 B ([32][16] + pad)
  _Float16 h1b[K_][72];             // 4608 B ([32][64] + pad)
};                                  // 6272 B total (16-aligned stride)
union SmemU {
  FpsLds  fps;
  SaSlice sa[16];
};

// ---------------------------------------------------------------------------
// sa math for ONE (b,m), executed by ONE wave on its own LDS slice.
// Byte-identical arithmetic to the verified sa_kernel v2 (r1-r12).
// ---------------------------------------------------------------------------
__device__ __forceinline__ void sa_wave(
    int b, int m, int lane,
    const float* __restrict__ x, const float* __restrict__ pos,
    const float* __restrict__ b1, const float* __restrict__ b2,
    const float* __restrict__ pos_s,
    const _Float16* __restrict__ w1t, const _Float16* __restrict__ w2t,
    float* __restrict__ x_out, SaSlice* sl)
{
  const int l15  = lane & 15;
  const int quad = lane >> 4;

  const float* pb = pos + (size_t)b * N_ * 3;
  const float* xb = x   + (size_t)b * N_ * DIN_;
  const size_t so = ((size_t)b * M_ + m) * 3;
  const float sx = pos_s[so + 0];
  const float sy = pos_s[so + 1];
  const float sz = pos_s[so + 2];
  const float R2 = (float)(0.2 * 0.2);

  // --- ball query: first K in-ball neighbors in index order (EXACT fp32) ---
  int cnt = 0;
  for (int base = 0; base < N_ && cnt < K_; base += 64) {
    int j = base + lane;
    float qx = pb[j * 3 + 0], qy = pb[j * 3 + 1], qz = pb[j * 3 + 2];
    bool win;
    {
#pragma clang fp contract(off)
      float dx = sx - qx, dy = sy - qy, dz = sz - qz;
      float d2 = (dx * dx + dy * dy) + dz * dz;
      win = d2 <= R2;
    }
    unsigned long long mk = __ballot(win);
    int rank = (int)__popcll(mk & ((1ull << lane) - 1ull));
    if (win) {
      int slot = cnt + rank;
      if (slot < K_) sl->nbr[slot] = j;
    }
    cnt += (int)__popcll(mk);
  }
  const int valid = cnt < K_ ? cnt : K_;   // uniform across wave, >= 1
  WAVE_LDS_SYNC();

  // --- gather -> featb (fp16): concat(x_j, pos_j - pos_s), invalid rows 0 ---
  for (int tq = lane; tq < K_ * 16; tq += 64) {
    int r = tq >> 4, i = tq & 15;
    float v = 0.f;
    if (r < valid) {
      int j = sl->nbr[r];
      if (i < DIN_) {
        v = xb[j * DIN_ + i];
      } else {
        float c = (i == 13) ? sx : (i == 14) ? sy : sz;
        float q = pb[j * 3 + (i - 13)];
        v = q - c;
      }
    }
    sl->featb[r][i] = (_Float16)v;
  }
  WAVE_LDS_SYNC();

  f16x8 fz;
#pragma unroll
  for (int i = 0; i < 8; ++i) fz[i] = (_Float16)0;

  // --- A1 / B1 fragments (K=32, k>=16 zero-padded on BOTH operands) ---
  f16x8 a1[2], b1f[4];
#pragma unroll
  for (int mt = 0; mt < 2; ++mt)
    a1[mt] = (quad < 2) ? *(const f16x8*)&sl->featb[mt * 16 + l15][quad * 8]
                        : fz;
#pragma unroll
  for (int nt = 0; nt < 4; ++nt)
    b1f[nt] = (quad < 2) ? *(const f16x8*)&w1t[(nt * 16 + l15) * 16 + quad * 8]
                         : fz;

  // --- MLP1 MFMA + bias + relu -> h1b (fp16) ---
#pragma unroll
  for (int mt = 0; mt < 2; ++mt) {
#pragma unroll
    for (int nt = 0; nt < 4; ++nt) {
      f32x4 c = {0.f, 0.f, 0.f, 0.f};
      c = __builtin_amdgcn_mfma_f32_16x16x32_f16(a1[mt], b1f[nt], c, 0, 0, 0);
      float bb = b1[nt * 16 + l15];
#pragma unroll
      for (int r = 0; r < 4; ++r) {
        float v = c[r] + bb;
        sl->h1b[mt * 16 + quad * 4 + r][nt * 16 + l15] =
            (_Float16)(v > 0.f ? v : 0.f);
      }
    }
  }
  WAVE_LDS_SYNC();

  // --- A2 fragments from h1b ---
  f16x8 a2[2][2];
#pragma unroll
  for (int mt = 0; mt < 2; ++mt)
#pragma unroll
    for (int kt = 0; kt < 2; ++kt)
      a2[mt][kt] = *(const f16x8*)&sl->h1b[mt * 16 + l15][kt * 32 + quad * 8];

  // --- MLP2 per N-tile: 4 MFMA + bias/relu/mask/max + cross-quad reduce ---
  float* o = x_out + ((size_t)b * M_ + m) * 128;
#pragma unroll
  for (int nt = 0; nt < 8; ++nt) {
    f16x8 b20 = *(const f16x8*)&w2t[(nt * 16 + l15) * 64 + 0 * 32 + quad * 8];
    f16x8 b21 = *(const f16x8*)&w2t[(nt * 16 + l15) * 64 + 1 * 32 + quad * 8];
    f32x4 c0 = {0.f, 0.f, 0.f, 0.f}, c1 = {0.f, 0.f, 0.f, 0.f};
    c0 = __builtin_amdgcn_mfma_f32_16x16x32_f16(a2[0][0], b20, c0, 0, 0, 0);
    c0 = __builtin_amdgcn_mfma_f32_16x16x32_f16(a2[0][1], b21, c0, 0, 0, 0);
    c1 = __builtin_amdgcn_mfma_f32_16x16x32_f16(a2[1][0], b20, c1, 0, 0, 0);
    c1 = __builtin_amdgcn_mfma_f32_16x16x32_f16(a2[1][1], b21, c1, 0, 0, 0);
    float bv = b2[nt * 16 + l15];
    float acc = -INFINITY;
#pragma unroll
    for (int r = 0; r < 4; ++r) {
      int row0 = quad * 4 + r;          // rows 0..15  (c0)
      int row1 = 16 + quad * 4 + r;     // rows 16..31 (c1)
      float v0 = c0[r] + bv; v0 = v0 > 0.f ? v0 : 0.f;
      float v1 = c1[r] + bv; v1 = v1 > 0.f ? v1 : 0.f;
      if (row0 < valid) acc = fmaxf(acc, v0);
      if (row1 < valid) acc = fmaxf(acc, v1);
    }
    acc = fmaxf(acc, __shfl_xor(acc, 16));
    acc = fmaxf(acc, __shfl_xor(acc, 32));
    if (quad == 0) o[nt * 16 + l15] = acc;
  }
}

// ---------------------------------------------------------------------------
// Fused cooperative kernel v2: blocks 0-7 = champion FPS; blocks 8+ = sa
// workers (16 waves/block, one (b,m) task per wave, grid-stride).
// r12 lesson: the naive progress channel slowed fps 1380->1452 via (a) all 8
// counters in ONE cache line ping-ponged by 3840 pollers, (b) RELEASE store
// draining vmcnt for same-iteration pos_s stores. v2: 128B-padded counters,
// DEFERRED release (publish s at iteration-s start, covering entries <=s-1
// whose stores are >=1 iteration old -> drain free), worker sleep 64.
// fps math/sort/prune/submit byte-identical to champion (r4/r9/r11).
// ---------------------------------------------------------------------------
__global__ __launch_bounds__(1024, 4) void fused_kernel(
    const float* __restrict__ x, const float* __restrict__ pos,
    const float* __restrict__ b1, const float* __restrict__ b2,
    const _Float16* __restrict__ w1t, const _Float16* __restrict__ w2t,
    float* __restrict__ pos_s, float* __restrict__ batch_s,
    float* __restrict__ x_out, int* __restrict__ progress)
{
  __shared__ SmemU u;
  const int t    = threadIdx.x;
  const int lane = t & 63;
  const int wid  = t >> 6;

  if (blockIdx.x < 8) {
    // ======================= FPS path (champion v3) =======================
    const int b = blockIdx.x;
    const float* p = pos + (size_t)b * N_ * 3;

    for (int mm = t; mm < M_; mm += 1024)
      batch_s[b * M_ + mm] = (float)b;
    if (t < 512) u.fps.vcur[t] = 0;
    if (t == 0) { u.fps.kslot[0] = 0ull; u.fps.kslot[1] = 0ull;
                  u.fps.kslot[2] = 0ull; }
    __syncthreads();

    // --- load points + 512-bin Morton histogram ---
    int vid[8];
#pragma unroll
    for (int i = 0; i < 8; ++i) {
      int j = t + 1024 * i;
      float xx = p[j * 3 + 0], yy = p[j * 3 + 1], zz = p[j * 3 + 2];
      u.fps.px[j] = xx; u.fps.py[j] = yy; u.fps.pz[j] = zz;
      int ix = (int)(xx * 8.f); ix = ix < 0 ? 0 : (ix > 7 ? 7 : ix);
      int iy = (int)(yy * 8.f); iy = iy < 0 ? 0 : (iy > 7 ? 7 : iy);
      int iz = (int)(zz * 8.f); iz = iz < 0 ? 0 : (iz > 7 ? 7 : iz);
      int v = (ix & 1) | ((iy & 1) << 1) | ((iz & 1) << 2) |
              (((ix >> 1) & 1) << 3) | (((iy >> 1) & 1) << 4) |
              (((iz >> 1) & 1) << 5) |
              ((ix >> 2) << 6) | ((iy >> 2) << 7) | ((iz >> 2) << 8);
      vid[i] = v;
      atomicAdd(&u.fps.vcur[v], 1);
    }
    __syncthreads();

    // --- exclusive prefix over 512 bins ---
    int h = 0, sc = 0;
    if (t < 512) {
      h = u.fps.vcur[t]; sc = h;
#pragma unroll
      for (int d = 1; d < 64; d <<= 1) {
        int o = __shfl_up(sc, d);
        if (lane >= d) sc += o;
      }
      if (lane == 63) u.fps.wsum[wid] = sc;
    }
    __syncthreads();
    if (t < 8) {
      int v = u.fps.wsum[t]; int inc = v;
#pragma unroll
      for (int d = 1; d < 8; d <<= 1) {
        int o = __shfl_up(inc, d);
        if (t >= d) inc += o;
      }
      u.fps.wsum[t] = inc - v;   // exclusive wave offset
    }
    __syncthreads();
    if (t < 512) { u.fps.vbase[t] = sc - h + u.fps.wsum[t >> 6];
                   u.fps.vcur[t] = 0; }
    __syncthreads();

    // --- scatter: rank per point ---
#pragma unroll
    for (int i = 0; i < 8; ++i) {
      int j = t + 1024 * i;
      int r = u.fps.vbase[vid[i]] + atomicAdd(&u.fps.vcur[vid[i]], 1);
      u.fps.r2o[r] = j;
    }
    __syncthreads();

    // --- gather: thread t owns ranks [8t,8t+8) (spatially tight) ---
    float px[8], py[8], pz[8], mind[8]; int oi[8];
#pragma unroll
    for (int i = 0; i < 8; ++i) {
      int o = u.fps.r2o[t * 8 + i];
      oi[i] = o;
      px[i] = u.fps.px[o]; py[i] = u.fps.py[o]; pz[i] = u.fps.pz[o];
      mind[i] = 1e10f;
    }
#pragma unroll
    for (int i = 0; i < 8; ++i) {
      asm volatile("" : "+v"(px[i]), "+v"(py[i]), "+v"(pz[i]));
    }

    // --- per-LANE bbox of the 8 owned points ---
    float bxmin = px[0], bxmax = px[0], bymin = py[0], bymax = py[0],
          bzmin = pz[0], bzmax = pz[0];
#pragma unroll
    for (int i = 1; i < 8; ++i) {
      bxmin = fminf(bxmin, px[i]); bxmax = fmaxf(bxmax, px[i]);
      bymin = fminf(bymin, py[i]); bymax = fmaxf(bymax, py[i]);
      bzmin = fminf(bzmin, pz[i]); bzmax = fmaxf(bzmax, pz[i]);
    }

    float lx = u.fps.px[0], ly = u.fps.py[0], lz = u.fps.pz[0];
    if (t == 0) {
      pos_s[(size_t)b * M_ * 3 + 0] = lx;
      pos_s[(size_t)b * M_ * 3 + 1] = ly;
      pos_s[(size_t)b * M_ * 3 + 2] = lz;
    }

    float ltm = 1e10f;                  // max of MY 8 minds (exact)
    float cwm = 0.f;                    // cached wave max (uniform)
    unsigned cmin = 0xFFFFFFFFu;        // cached wave tie-min orig idx
    int slm = 1;   // s % 3
    int rsm = 0;   // (s+2) % 3

    for (int s = 1; s < M_; ++s) {
      float cx = fmaxf(fmaxf(bxmin - lx, lx - bxmax), 0.f);
      float cy = fmaxf(fmaxf(bymin - ly, ly - bymax), 0.f);
      float cz = fmaxf(fmaxf(bzmin - lz, lz - bzmax), 0.f);
      float LB = (cx * cx + cy * cy) + cz * cz;
      bool lp = (LB * 0.999999f < ltm);          // lane might change
      if (__ballot(lp) != 0ull) {                // wave-uniform branch
        float tmax;
        {
#pragma clang fp contract(off)
#pragma unroll
          for (int i = 0; i < 8; ++i) {
            float dx = px[i] - lx, dy = py[i] - ly, dz = pz[i] - lz;
            float d  = (dx * dx + dy * dy) + dz * dz;  // EXACT: jnp order
            mind[i]  = fminf(mind[i], d);
          }
          float m0 = fmaxf(mind[0], mind[1]), m1 = fmaxf(mind[2], mind[3]);
          float m2 = fmaxf(mind[4], mind[5]), m3 = fmaxf(mind[6], mind[7]);
          tmax = fmaxf(fmaxf(m0, m1), fmaxf(m2, m3));
        }
        ltm = tmax;
        const float wm = wave_reduce_max(tmax);
        unsigned cc = 0xFFFFFFFFu;   // smallest orig index among my ties
#pragma unroll
        for (int i = 0; i < 8; ++i) {
          unsigned cand = (mind[i] == wm) ? (unsigned)oi[i] : 0xFFFFFFFFu;
          cc = cc < cand ? cc : cand;
        }
        cmin = wave_reduce_min_u32(cc);
        cwm = wm;
      }
      // one submit per wave (fresh or cached)
      if (lane == 0) {
        unsigned long long key =
            ((unsigned long long)__float_as_uint(cwm) << 32) |
            (unsigned long long)(0xFFFFFFFFu - cmin);
        atomicMax(&u.fps.kslot[slm], key);
      }
      __syncthreads();                               // the ONE barrier
      if (t == 0) u.fps.kslot[rsm] = 0ull;
      const unsigned long long kk = u.fps.kslot[slm];
      const int wj  = (int)(0xFFFFFFFFu - (unsigned int)(kk & 0xFFFFFFFFull));
      const int wju = (int)__builtin_amdgcn_readfirstlane(wj);
      lx = u.fps.px[wju]; ly = u.fps.py[wju]; lz = u.fps.pz[wju];
      if (t == 0) {
        // DEFERRED release: publish entries <= s-1 (stores >=1 iter old,
        // vmcnt drain ~free). Padded counter: no false sharing.
        if ((s & 31) == 0)
          __hip_atomic_store(&progress[b << 5], s, __ATOMIC_RELEASE,
                             __HIP_MEMORY_SCOPE_AGENT);
        size_t o2 = ((size_t)b * M_ + s) * 3;
        pos_s[o2 + 0] = lx; pos_s[o2 + 1] = ly; pos_s[o2 + 2] = lz;
      }
      slm = (slm == 2) ? 0 : slm + 1;
      rsm = (rsm == 2) ? 0 : rsm + 1;
    }
    // final release: all M_ entries written
    if (t == 0)
      __hip_atomic_store(&progress[b << 5], M_, __ATOMIC_RELEASE,
                         __HIP_MEMORY_SCOPE_AGENT);
  } else {
    // ======================= SA worker path =======================
    SaSlice* sl = &u.sa[wid];
    const int wgw = (blockIdx.x - 8) * 16 + wid;     // worker wave id
    for (int task = wgw; task < B_ * M_; task += NWRK * 16) {
      const int b = task >> 11, m = task & (M_ - 1);
      if (lane == 0) {
        while (__hip_atomic_load(&progress[b << 5], __ATOMIC_RELAXED,
                                 __HIP_MEMORY_SCOPE_AGENT) <= m)
          __builtin_amdgcn_s_sleep(64);   // ~1.7us poll; release cadence ~21us
      }
      __threadfence();   // acquire: fps's pos_s writes now visible
      sa_wave(b, m, lane, x, pos, b1, b2, pos_s, w1t, w2t, x_out, sl);
    }
  }
}

// ---------------------------------------------------------------------------
// Prep: weight transpose/convert + zero the (padded) progress counters.
// ---------------------------------------------------------------------------
__global__ __launch_bounds__(256) void prep_kernel(
    const float* __restrict__ W1, const float* __restrict__ W2,
    _Float16* __restrict__ w1t, _Float16* __restrict__ w2t,
    int* __restrict__ progress)
{
  int t = blockIdx.x * 256 + threadIdx.x;
  if (t < 8192) {
    int n = t >> 6, k = t & 63;
    w2t[t] = (_Float16)W2[k * 128 + n];
  }
  int u = t - 8192;
  if (u >= 0 && u < 1024) {
    int n = u >> 4, k = u & 15;
    w1t[u] = (_Float16)W1[k * 64 + n];
  }
  if (blockIdx.x == 0) progress[threadIdx.x] = 0;   // 256 padded ints
}

// ---------------------------------------------------------------------------
extern "C" void kernel_launch(void* const* d_in, const int* in_sizes, int n_in,
                              void* d_out, int out_size, void* d_ws, size_t ws_size,
                              hipStream_t stream) {
  (void)in_sizes; (void)n_in; (void)ws_size; (void)out_size;
  const float* x   = (const float*)d_in[0];
  const float* pos = (const float*)d_in[1];
  // d_in[2] = batch (unused: always broadcast arange(B))
  const float* W1  = (const float*)d_in[3];
  const float* b1  = (const float*)d_in[4];
  const float* W2  = (const float*)d_in[5];
  const float* b2  = (const float*)d_in[6];

  float* out     = (float*)d_out;
  float* x_out   = out;                                  // [B, M, 128]
  float* pos_s   = out + (size_t)B_ * M_ * 128;          // [B, M, 3]
  float* batch_s = pos_s + (size_t)B_ * M_ * 3;          // [B, M]

  _Float16* w1t = (_Float16*)d_ws;                       // [64][16]
  _Float16* w2t = w1t + 1024;                            // [128][64]
  int* progress = (int*)(w2t + 8192);                    // [8*32] padded

  prep_kernel<<<36, 256, 0, stream>>>(W1, W2, w1t, w2t, progress);

  void* kargs[] = {
      (void*)&x, (void*)&pos, (void*)&b1, (void*)&b2,
      (void*)&w1t, (void*)&w2t, (void*)&pos_s, (void*)&batch_s,
      (void*)&x_out, (void*)&progress};
  hipLaunchCooperativeKernel((const void*)fused_kernel,
                             dim3(NBLK), dim3(1024), kargs, 0, stream);
}